// Round 7
// baseline (326.301 us; speedup 1.0000x reference)
//
#include <hip/hip_runtime.h>

// Round 7: coarser padded buckets (RN 128->512) to kill k_bin2p's 4-5x
// write amplification (runs 80B -> 320B) + 2x bin grid for latency hiding.
// Everything else keeps the round-6 structure (split high-occupancy gather2,
// fused g1c1, fused combine2+cls, in-place bucket counting sort).
//
// ws: h1f[N*32] aggT[N*32] aggI[N*32] (f32) | h1b[N*32] xp[N*8] (bf16) |
//     curT curI [KMAX] | startT degT startI degI [N] | binT binI [K*CAP]

#define BLK 256
#define RN 512            // nodes per bucket
#define KMAX 256          // max buckets (N <= 131072)
#define CAP 11264         // bucket capacity: mean E/K=10204, +10.5 sigma

typedef unsigned short us8 __attribute__((ext_vector_type(8)));

__device__ inline unsigned short f2bf(float f) {
  unsigned u = __float_as_uint(f);
  return (unsigned short)((u + 0x7FFFu + ((u >> 16) & 1u)) >> 16);
}
__device__ inline float bf2f(unsigned short h) {
  return __uint_as_float(((unsigned)h) << 16);
}

// ---------------- prep: x -> bf16 padded rows; also init bucket cursors ----
__global__ __launch_bounds__(BLK) void k_prep(const float* __restrict__ x,
                                              unsigned short* __restrict__ xp,
                                              int* __restrict__ curT,
                                              int* __restrict__ curI, int N,
                                              int K) {
  int gid = blockIdx.x * BLK + threadIdx.x;
  if (gid < K) {
    curT[gid] = gid * CAP;
    curI[gid] = gid * CAP;
  }
  if (gid >= N * 8) return;
  int n = gid >> 3, c = gid & 7;
  xp[gid] = (c < 6) ? f2bf(x[n * 6 + c]) : (unsigned short)0;
}

// bin edges into padded buckets (dst>>9): LDS hist -> global reserve -> write
__global__ __launch_bounds__(BLK) void k_bin2p(
    const int* __restrict__ eiT, int ET, int* __restrict__ curT,
    int* __restrict__ binT, const int* __restrict__ eiI, int EI,
    int* __restrict__ curI, int* __restrict__ binI, int K) {
  const int* ei = blockIdx.y ? eiI : eiT;
  int E = blockIdx.y ? EI : ET;
  int* cur = blockIdx.y ? curI : curT;
  int* binned = blockIdx.y ? binI : binT;
  __shared__ int lh[KMAX];
  int t = threadIdx.x;
  for (int i = t; i < K; i += BLK) lh[i] = 0;
  __syncthreads();
  int nb = gridDim.x;
  int chunk = (E + nb - 1) / nb;
  int cs = blockIdx.x * chunk;
  int ce = min(E, cs + chunk);
  for (int e = cs + t; e < ce; e += BLK) atomicAdd(&lh[ei[E + e] >> 9], 1);
  __syncthreads();
  for (int b = t; b < K; b += BLK) {
    int c = lh[b];
    lh[b] = c ? atomicAdd(&cur[b], c) : 0;
  }
  __syncthreads();
  for (int e = cs + t; e < ce; e += BLK) {
    int src = ei[e];
    int d = ei[E + e];
    int pos = atomicAdd(&lh[d >> 9], 1);
    binned[pos] = (src << 9) | (d & 511);
  }
}

// per-bucket counting sort, in place (stage bucket in LDS), emit start/deg
__global__ __launch_bounds__(512) void k_sortcsr2p(
    int* __restrict__ binT, const int* __restrict__ curT,
    int* __restrict__ startT, int* __restrict__ degT, int* __restrict__ binI,
    const int* __restrict__ curI, int* __restrict__ startI,
    int* __restrict__ degI, int N) {
  int* bin = blockIdx.y ? binI : binT;
  const int* cur = blockIdx.y ? curI : curT;
  int* start = blockIdx.y ? startI : startT;
  int* deg = blockIdx.y ? degI : degT;
  __shared__ int ebuf[CAP];
  __shared__ int h[RN], s[RN], c2[RN];
  int t = threadIdx.x, b = blockIdx.x;
  int e0 = b * CAP;
  int cnt = min(cur[b] - e0, CAP);
  h[t] = 0;
  __syncthreads();
  for (int i = t; i < cnt; i += 512) {
    int p = bin[e0 + i];
    ebuf[i] = p;
    atomicAdd(&h[p & 511], 1);
  }
  __syncthreads();
  s[t] = h[t];
  __syncthreads();
  for (int off = 1; off < 512; off <<= 1) {
    int v = (t >= off) ? s[t - off] : 0;
    __syncthreads();
    s[t] += v;
    __syncthreads();
  }
  int excl = s[t] - h[t];
  int n = b * RN + t;
  if (n < N) {
    start[n] = e0 + excl;
    deg[n] = h[t];
  }
  c2[t] = excl;
  __syncthreads();
  for (int i = t; i < cnt; i += 512) {
    int p = ebuf[i];
    int pos = atomicAdd(&c2[p & 511], 1);
    bin[e0 + pos] = p >> 9;
  }
}

// ---------------- fused layer 1: gather x + transform ----------------
// block = 128 nodes, 2 threads/node
#define GN1 128
__global__ __launch_bounds__(BLK) void k_g1c1(
    const unsigned short* __restrict__ xp, const float* __restrict__ x,
    const int* __restrict__ startT, const int* __restrict__ degT,
    const int* __restrict__ csrT, const int* __restrict__ startI,
    const int* __restrict__ degI, const int* __restrict__ csrI,
    const float* __restrict__ Wt, const float* __restrict__ bt,
    const float* __restrict__ Wi, const float* __restrict__ bi,
    const float* __restrict__ Wr, const float* __restrict__ br,
    float* __restrict__ h1f, unsigned short* __restrict__ h1b, int N) {
  __shared__ float sGT[GN1 * 8], sGI[GN1 * 8], sx[GN1 * 6];
  __shared__ float sWt[192], sWi[192], sWr[192], sb[96];
  __shared__ float sdT[GN1], sdI[GN1];
  int t = threadIdx.x, b = blockIdx.x;
  if (t < 192) { sWt[t] = Wt[t]; sWi[t] = Wi[t]; sWr[t] = Wr[t]; }
  if (t < 32) { sb[t] = bt[t]; sb[32 + t] = bi[t]; sb[64 + t] = br[t]; }
  for (int i = t; i < GN1 * 6; i += BLK) {
    int g = b * GN1 * 6 + i;
    sx[i] = (g < N * 6) ? x[g] : 0.0f;
  }
  int nl = t >> 1, sub = t & 1;
  int n = b * GN1 + nl;
  float a0 = 0.f, a1 = 0.f, a2 = 0.f, a3 = 0.f;
  float c0 = 0.f, c1 = 0.f, c2 = 0.f, c3 = 0.f;
  int dT = 0, dI = 0;
  if (n < N) {
    {
      int s0 = startT[n];
      dT = degT[n];
      const int* c = csrT + s0;
      for (int i = 0; i < dT; ++i) {
        int src = c[i];
        ushort4 v = *(const ushort4*)(xp + (size_t)src * 8 + sub * 4);
        a0 += bf2f(v.x); a1 += bf2f(v.y); a2 += bf2f(v.z); a3 += bf2f(v.w);
      }
    }
    {
      int s0 = startI[n];
      dI = degI[n];
      const int* c = csrI + s0;
      for (int i = 0; i < dI; ++i) {
        int src = c[i];
        ushort4 v = *(const ushort4*)(xp + (size_t)src * 8 + sub * 4);
        c0 += bf2f(v.x); c1 += bf2f(v.y); c2 += bf2f(v.z); c3 += bf2f(v.w);
      }
    }
  }
  int base = nl * 8 + sub * 4;
  sGT[base + 0] = a0; sGT[base + 1] = a1; sGT[base + 2] = a2; sGT[base + 3] = a3;
  sGI[base + 0] = c0; sGI[base + 1] = c1; sGI[base + 2] = c2; sGI[base + 3] = c3;
  if (sub == 0) { sdT[nl] = (float)dT; sdI[nl] = (float)dI; }
  __syncthreads();
  for (int idx = t; idx < GN1 * 32; idx += BLK) {
    int m = idx >> 5, j = idx & 31;
    int nn = b * GN1 + m;
    if (nn >= N) break;
    float fdT = sdT[m], fdI = sdI[m];
    float invI = 1.0f / fmaxf(fdI, 1.0f);
    float gate = (fdI > 0.0f) ? 1.0f : 0.0f;
    float acc = fdT * sb[j] + gate * sb[32 + j] + sb[64 + j];
#pragma unroll
    for (int k = 0; k < 6; ++k) {
      acc += sGT[m * 8 + k] * sWt[k * 32 + j];
      acc += sGI[m * 8 + k] * invI * sWi[k * 32 + j];
      acc += sx[m * 6 + k] * sWr[k * 32 + j];
    }
    acc = fmaxf(acc, 0.0f);
    h1f[(size_t)nn * 32 + j] = acc;
    h1b[(size_t)nn * 32 + j] = f2bf(acc);
  }
}

// ---------------- layer-2 gather: 4 thr/node, 16B bf16 loads, y=edge type ---
__global__ __launch_bounds__(BLK) void k_gather2(
    const unsigned short* __restrict__ h1b, const int* __restrict__ startT,
    const int* __restrict__ degT, const int* __restrict__ csrT,
    const int* __restrict__ startI, const int* __restrict__ degI,
    const int* __restrict__ csrI, float* __restrict__ aggT,
    float* __restrict__ aggI, int N) {
  const int* start = blockIdx.y ? startI : startT;
  const int* deg = blockIdx.y ? degI : degT;
  const int* csr = blockIdx.y ? csrI : csrT;
  float* agg = blockIdx.y ? aggI : aggT;
  int gid = blockIdx.x * BLK + threadIdx.x;
  int n = gid >> 2;
  if (n >= N) return;
  int sub = gid & 3;
  float a0 = 0.f, a1 = 0.f, a2 = 0.f, a3 = 0.f;
  float a4 = 0.f, a5 = 0.f, a6 = 0.f, a7 = 0.f;
  int s0 = start[n], d = deg[n];
  const int* c = csr + s0;
  int i = 0;
  for (; i + 2 <= d; i += 2) {
    int src0 = c[i], src1 = c[i + 1];
    us8 v0 = *(const us8*)(h1b + (size_t)src0 * 32 + sub * 8);
    us8 v1 = *(const us8*)(h1b + (size_t)src1 * 32 + sub * 8);
    a0 += bf2f(v0[0]) + bf2f(v1[0]);
    a1 += bf2f(v0[1]) + bf2f(v1[1]);
    a2 += bf2f(v0[2]) + bf2f(v1[2]);
    a3 += bf2f(v0[3]) + bf2f(v1[3]);
    a4 += bf2f(v0[4]) + bf2f(v1[4]);
    a5 += bf2f(v0[5]) + bf2f(v1[5]);
    a6 += bf2f(v0[6]) + bf2f(v1[6]);
    a7 += bf2f(v0[7]) + bf2f(v1[7]);
  }
  if (i < d) {
    int src0 = c[i];
    us8 v0 = *(const us8*)(h1b + (size_t)src0 * 32 + sub * 8);
    a0 += bf2f(v0[0]); a1 += bf2f(v0[1]); a2 += bf2f(v0[2]); a3 += bf2f(v0[3]);
    a4 += bf2f(v0[4]); a5 += bf2f(v0[5]); a6 += bf2f(v0[6]); a7 += bf2f(v0[7]);
  }
  float4 o0 = {a0, a1, a2, a3}, o1 = {a4, a5, a6, a7};
  float* p = agg + (size_t)n * 32 + sub * 8;
  *(float4*)p = o0;
  *(float4*)(p + 4) = o1;
}

// ---------------- combine2 + classifier ----------------
__global__ __launch_bounds__(BLK) void k_combine2cls(
    const float* __restrict__ aggT, const float* __restrict__ aggI,
    const float* __restrict__ h1, const int* __restrict__ degT,
    const int* __restrict__ degI, const float* __restrict__ Wt,
    const float* __restrict__ bt, const float* __restrict__ Wi,
    const float* __restrict__ bi, const float* __restrict__ Wr,
    const float* __restrict__ br, const float* __restrict__ Wc,
    const float* __restrict__ bc, float* __restrict__ out, int N) {
  __shared__ float sWt[1024], sWi[1024], sWr[1024], sWc[224];
  __shared__ float sb[96], sbc[7];
  __shared__ float hT[BLK], hI[BLK], hR[BLK], hs2[BLK];
  __shared__ float sdT[8], sdI[8];
  int t = threadIdx.x;
  for (int i = t; i < 1024; i += BLK) {
    sWt[i] = Wt[i];
    sWi[i] = Wi[i];
    sWr[i] = Wr[i];
  }
  if (t < 224) sWc[t] = Wc[t];
  if (t < 32) { sb[t] = bt[t]; sb[32 + t] = bi[t]; sb[64 + t] = br[t]; }
  if (t < 7) sbc[t] = bc[t];
  int gid = blockIdx.x * BLK + t;
  int nodeBase = (blockIdx.x * BLK) >> 5;
  if (gid < N * 32) {
    hT[t] = aggT[gid];
    hI[t] = aggI[gid];
    hR[t] = h1[gid];
  } else {
    hT[t] = 0.f; hI[t] = 0.f; hR[t] = 0.f;
  }
  if (t < 8) {
    int n = nodeBase + t;
    sdT[t] = (n < N) ? (float)degT[n] : 0.f;
    sdI[t] = (n < N) ? (float)degI[n] : 0.f;
  }
  __syncthreads();
  int j = t & 31, ln = t >> 5;
  float dT = sdT[ln], dI = sdI[ln];
  float invI = 1.0f / fmaxf(dI, 1.0f);
  float gate = (dI > 0.0f) ? 1.0f : 0.0f;
  float acc = dT * sb[j] + gate * sb[32 + j] + sb[64 + j];
#pragma unroll
  for (int k = 0; k < 32; ++k) {
    acc += hT[ln * 32 + k] * sWt[k * 32 + j];
    acc += hI[ln * 32 + k] * invI * sWi[k * 32 + j];
    acc += hR[ln * 32 + k] * sWr[k * 32 + j];
  }
  hs2[t] = fmaxf(acc, 0.0f);
  __syncthreads();
  if (j < 7) {
    int n = nodeBase + ln;
    if (n < N) {
      float a = sbc[j];
#pragma unroll
      for (int k = 0; k < 32; ++k) a += hs2[ln * 32 + k] * sWc[k * 7 + j];
      out[(size_t)n * 7 + j] = a;
    }
  }
}

extern "C" void kernel_launch(void* const* d_in, const int* in_sizes, int n_in,
                              void* d_out, int out_size, void* d_ws,
                              size_t ws_size, hipStream_t stream) {
  const float* x   = (const float*)d_in[0];
  const int* ei_t  = (const int*)d_in[1];
  const int* ei_i  = (const int*)d_in[2];
  const float* W1t = (const float*)d_in[3];
  const float* b1t = (const float*)d_in[4];
  const float* W1i = (const float*)d_in[5];
  const float* b1i = (const float*)d_in[6];
  const float* W1r = (const float*)d_in[7];
  const float* b1r = (const float*)d_in[8];
  const float* W2t = (const float*)d_in[9];
  const float* b2t = (const float*)d_in[10];
  const float* W2i = (const float*)d_in[11];
  const float* b2i = (const float*)d_in[12];
  const float* W2r = (const float*)d_in[13];
  const float* b2r = (const float*)d_in[14];
  const float* Wc  = (const float*)d_in[15];
  const float* bc  = (const float*)d_in[16];
  float* out = (float*)d_out;

  const int N  = in_sizes[0] / 6;
  const int E  = in_sizes[1] / 2;
  const int Ei = in_sizes[2] / 2;
  const int K  = (N + RN - 1) / RN;

  float* h1f  = (float*)d_ws;
  float* aggT = h1f + (size_t)N * 32;
  float* aggI = aggT + (size_t)N * 32;
  unsigned short* h1b = (unsigned short*)(aggI + (size_t)N * 32);
  unsigned short* xp  = h1b + (size_t)N * 32;
  int* curT   = (int*)(xp + (size_t)N * 8);
  int* curI   = curT + KMAX;
  int* startT = curI + KMAX;
  int* degT   = startT + N;
  int* startI = degT + N;
  int* degI   = startI + N;
  int* binT   = degI + N;
  int* binI   = binT + (size_t)K * CAP;

  const int gN8  = (N * 8 + BLK - 1) / BLK;
  const int gG1  = (N + GN1 - 1) / GN1;
  const int gG2  = (N * 4 + BLK - 1) / BLK;
  const int gC2  = (N * 32 + BLK - 1) / BLK;
  const int NB   = 256;

  // ---- build ----
  k_prep<<<gN8, BLK, 0, stream>>>(x, xp, curT, curI, N, K);
  k_bin2p<<<dim3(NB, 2), BLK, 0, stream>>>(ei_t, E, curT, binT, ei_i, Ei,
                                           curI, binI, K);
  k_sortcsr2p<<<dim3(K, 2), 512, 0, stream>>>(binT, curT, startT, degT, binI,
                                              curI, startI, degI, N);

  // ---- Layer 1 (fused gather+transform) ----
  k_g1c1<<<gG1, BLK, 0, stream>>>(xp, x, startT, degT, binT, startI, degI,
                                  binI, W1t, b1t, W1i, b1i, W1r, b1r, h1f,
                                  h1b, N);

  // ---- Layer 2 (split: high-occupancy gather, then combine+cls) ----
  k_gather2<<<dim3(gG2, 2), BLK, 0, stream>>>(h1b, startT, degT, binT, startI,
                                              degI, binI, aggT, aggI, N);
  k_combine2cls<<<gC2, BLK, 0, stream>>>(aggT, aggI, h1f, degT, degI, W2t,
                                         b2t, W2i, b2i, W2r, b2r, Wc, bc, out,
                                         N);
}